// Round 9
// baseline (258.511 us; speedup 1.0000x reference)
//
#include <hip/hip_runtime.h>
#include <hip/hip_bf16.h>

#define DIM   384
#define HEADS 12
#define K2    9
#define HH    56
#define WW    56
#define HWP   3136
#define BB    8
#define AO    972      // attn-logit channels
#define AOP   1024     // padded (lT row stride)
#define MCAT  1408     // 384 (v) + 1024 (attn) concatenated GEMM rows
#define PP    3200     // pixels padded to 25*128

typedef __hip_bfloat16 bf16;
typedef short bf16x8 __attribute__((ext_vector_type(8)));
typedef short bf16x4v __attribute__((ext_vector_type(4)));
typedef float f32x4 __attribute__((ext_vector_type(4)));

static __device__ __forceinline__ float b2f(bf16 v) { return __bfloat162float(v); }
static __device__ __forceinline__ float bs2f(short s) {
    return __uint_as_float(((unsigned int)(unsigned short)s) << 16);
}
static __device__ __forceinline__ short f2bs(float f) {
    __hip_bfloat16 h = __float2bfloat16(f);
    return *(short*)&h;
}

// async global->LDS, 16B per lane. LDS dest must be wave-uniform base + lane*16.
static __device__ __forceinline__ void gl_lds16(const bf16* g, bf16* l) {
    __builtin_amdgcn_global_load_lds(
        (const __attribute__((address_space(1))) unsigned int*)g,
        (__attribute__((address_space(3))) unsigned int*)l, 16, 0, 0);
}

// ---------------------------------------------------------------------------
// x [b][384][3136] fp32  ->  xT [b][3200][384] bf16 (zero pad rows)
// ---------------------------------------------------------------------------
__global__ __launch_bounds__(256) void xpose_kernel(
        const float* __restrict__ x, bf16* __restrict__ xT) {
    const int lane = threadIdx.x & 63, w = threadIdx.x >> 6;
    const int p = blockIdx.x * 64 + lane;
    const int b = blockIdx.y;
    bf16* dst = xT + ((size_t)b * PP + p) * DIM;
    if (p >= HWP) {
        bf16x8 z = {};
        for (int cg = w; cg < 48; cg += 4) *(bf16x8*)(dst + cg * 8) = z;
        return;
    }
    const float* src = x + (size_t)b * DIM * HWP + p;
    for (int cg = w; cg < 48; cg += 4) {
        bf16x8 v;
#pragma unroll
        for (int j = 0; j < 8; j++) v[j] = f2bs(src[(size_t)(cg * 8 + j) * HWP]);
        *(bf16x8*)(dst + cg * 8) = v;
    }
}

// all three weight tensors -> bf16 in one launch
// wcat = [v_w(384) ; attn_w(972) ; zeros(52)], wp = proj_w
__global__ __launch_bounds__(256) void wconv_all_kernel(
        const float* __restrict__ v_w, const float* __restrict__ attn_w,
        const float* __restrict__ proj_w, bf16* __restrict__ wcat,
        bf16* __restrict__ wp) {
    const int idx = blockIdx.x * 256 + threadIdx.x;
    const int NCAT = MCAT * DIM;
    if (idx < NCAT) {
        const int row = idx / DIM, col = idx % DIM;
        float v;
        if (row < 384) v = v_w[row * DIM + col];
        else { const int r2 = row - 384; v = (r2 < AO) ? attn_w[r2 * DIM + col] : 0.f; }
        *(short*)&wcat[idx] = f2bs(v);
    } else {
        const int j = idx - NCAT;
        if (j < 384 * DIM) *(short*)&wp[j] = f2bs(proj_w[j]);
    }
}

// ---------------------------------------------------------------------------
// GEMM main loop v2: 128x128 tile, BK=32, 4 waves x (4x4) 16x16x32 MFMA.
//  - A-fragments loaded DIRECT from global (weights, L2-resident) — no lA.
//  - B-tile staged via global_load_lds with XOR swizzle: k-octet kq of row m
//    stored at position (kq + (m>>1)) & 3, so 8 consecutive reader lanes
//    cover all 8 LDS 16B-granule bank groups (was 2 -> 8-way conflicts).
// ---------------------------------------------------------------------------
#define GEMM_MAIN_LOOP_V2(Ab, Bb, lB, acc)                                     \
    {                                                                          \
    const int swz = ((quad + (l16 >> 1)) & 3) * 8;                             \
    for (int k0 = 0; k0 < DIM; k0 += 32) {                                     \
        _Pragma("unroll")                                                      \
        for (int r = 0; r < 2; r++) {                                          \
            int idx = r * 256 + t;                                             \
            int row = idx >> 2;                                                \
            int kq = ((idx & 3) - (idx >> 3)) & 3;                             \
            gl_lds16(Bb + (size_t)row * DIM + k0 + kq * 8, lB + idx * 8);      \
        }                                                                      \
        bf16x8 af[4];                                                          \
        _Pragma("unroll")                                                      \
        for (int mt = 0; mt < 4; mt++)                                         \
            af[mt] = *(const bf16x8*)(Ab +                                     \
                (size_t)(wm * 64 + mt * 16 + l16) * DIM + k0 + quad * 8);      \
        __syncthreads();                                                       \
        bf16x8 bfr[4];                                                         \
        _Pragma("unroll")                                                      \
        for (int nt = 0; nt < 4; nt++)                                         \
            bfr[nt] = *(const bf16x8*)(lB +                                    \
                (wn * 64 + nt * 16 + l16) * 32 + swz);                         \
        _Pragma("unroll")                                                      \
        for (int mt = 0; mt < 4; mt++)                                         \
            _Pragma("unroll")                                                  \
            for (int nt = 0; nt < 4; nt++)                                     \
                acc[mt][nt] = __builtin_amdgcn_mfma_f32_16x16x32_bf16(         \
                    af[mt], bfr[nt], acc[mt][nt], 0, 0, 0);                    \
        __syncthreads();                                                       \
    }                                                                          \
    }

// ---------------------------------------------------------------------------
// Merged GEMM1+2: A = [wv(384) ; wa(1024)] -> vT (stride 384, +bias) and
// lT (stride 1024). Transposed bf16 outputs via per-wave LDS repack
// (no barriers: repack buffers are wave-private; DS ops are wave-ordered).
// ---------------------------------------------------------------------------
__global__ __launch_bounds__(256) void gemm12_kernel(
        const bf16* __restrict__ A, const bf16* __restrict__ Bt,
        const float* __restrict__ bias, bf16* __restrict__ vT,
        bf16* __restrict__ lT) {
    __shared__ bf16 lB[4096];
    __shared__ bf16 wrep[4 * 1152];
    const int t = threadIdx.x;
    const int lane = t & 63, w = t >> 6;
    const int wm = w & 1, wn = w >> 1;
    const int quad = lane >> 4, l16 = lane & 15;
    const int n0 = blockIdx.x * 128;
    const int m0 = blockIdx.y * 128;
    const int b = blockIdx.z;

    const bf16* Ab = A + (size_t)m0 * DIM;
    const bf16* Bb = Bt + ((size_t)b * PP + n0) * DIM;

    f32x4 acc[4][4] = {};
    GEMM_MAIN_LOOP_V2(Ab, Bb, lB, acc)

    const bool isv = (m0 < 384);
    bf16* outp = isv ? vT : lT;
    const int ostr = isv ? DIM : AOP;
    const int ch0 = isv ? m0 : m0 - 384;

    bf16* wbuf = wrep + w * 1152;   // wave-private, row stride 72 bf16
    const int nr = lane >> 2;
    const int mc = (lane & 3) * 16;
#pragma unroll
    for (int nt = 0; nt < 4; nt++) {
#pragma unroll
        for (int mt = 0; mt < 4; mt++) {
            float4 bi = make_float4(0.f, 0.f, 0.f, 0.f);
            if (isv) bi = *(const float4*)(bias + ch0 + wm * 64 + mt * 16 + quad * 4);
            bf16x4v pk;
            pk[0] = f2bs(acc[mt][nt][0] + bi.x);
            pk[1] = f2bs(acc[mt][nt][1] + bi.y);
            pk[2] = f2bs(acc[mt][nt][2] + bi.z);
            pk[3] = f2bs(acc[mt][nt][3] + bi.w);
            *(bf16x4v*)(wbuf + l16 * 72 + mt * 16 + quad * 4) = pk;
        }
        bf16x8 v0 = *(const bf16x8*)(wbuf + nr * 72 + mc);
        bf16x8 v1 = *(const bf16x8*)(wbuf + nr * 72 + mc + 8);
        const int p = n0 + wn * 64 + nt * 16 + nr;
        if (p < HWP) {
            bf16* dp = outp + ((size_t)b * PP + p) * ostr + ch0 + wm * 64 + mc;
            *(bf16x8*)dp = v0;
            *(bf16x8*)(dp + 8) = v1;
        }
    }
}

// ---------------------------------------------------------------------------
// GEMM4: planar fp32 out [b][384][3136]
// ---------------------------------------------------------------------------
__global__ __launch_bounds__(256) void gemm_planar_kernel(
        const bf16* __restrict__ A, const bf16* __restrict__ Bt,
        float* __restrict__ out) {
    __shared__ bf16 lB[4096];
    const int t = threadIdx.x;
    const int lane = t & 63, w = t >> 6;
    const int wm = w & 1, wn = w >> 1;
    const int quad = lane >> 4, l16 = lane & 15;
    const int n0 = blockIdx.x * 128;
    const int m0 = blockIdx.y * 128;
    const int b = blockIdx.z;

    const bf16* Ab = A + (size_t)m0 * DIM;
    const bf16* Bb = Bt + ((size_t)b * PP + n0) * DIM;

    f32x4 acc[4][4] = {};
    GEMM_MAIN_LOOP_V2(Ab, Bb, lB, acc)

#pragma unroll
    for (int mt = 0; mt < 4; mt++) {
#pragma unroll
        for (int nt = 0; nt < 4; nt++) {
            int p = n0 + wn * 64 + nt * 16 + l16;
            if (p >= HWP) continue;
#pragma unroll
            for (int reg = 0; reg < 4; reg++) {
                int o = m0 + wm * 64 + mt * 16 + quad * 4 + reg;
                out[((size_t)b * DIM + o) * HWP + p] = acc[mt][nt][reg];
            }
        }
    }
}

// ---------------------------------------------------------------------------
// attn+fold (unchanged from round 8): 8 pixels per block, 384 threads.
// P stored bf16: LDS 29 KB -> high occupancy; stage-A direct global reads.
// ---------------------------------------------------------------------------
__global__ __launch_bounds__(384) void attn_fold_kernel(
        const bf16* __restrict__ lT, const bf16* __restrict__ vT,
        bf16* __restrict__ cT) {
    __shared__ bf16 P[8 * 9 * 12 * 9];     // [px][i][n][d]  19440 B
    __shared__ float Wf[8 * 25 * 12];      // [px][off][n]    9600 B
    const int t = threadIdx.x;
    const int b = blockIdx.y;
    const int pix0 = blockIdx.x * 8;
    const int Y = pix0 / WW, X0 = pix0 % WW;

    // ---- stage A: softmaxes at window centers (direct global reads)
    for (int r = t; r < 864; r += 384) {
        const int px = r / 108, rem = r % 108;
        const int i = rem / 12, n = rem % 12;
        const int ir = i / 3, ic = i % 3;
        const int yi = Y + 1 - ir, xi = X0 + px + 1 - ic;
        bf16* Pd = &P[r * 9];   // r*9 == ((px*9+i)*12+n)*9
        if (yi < 0 || yi >= HH || xi < 0 || xi >= WW) {
#pragma unroll
            for (int d = 0; d < K2; d++) *(short*)&Pd[d] = 0;
        } else {
            const bf16* base = lT + ((size_t)b * PP + yi * WW + xi) * AOP + i * 108 + n;
            float lv[K2];
            float m = -1e30f;
#pragma unroll
            for (int d = 0; d < K2; d++) {
                lv[d] = b2f(base[d * 12]);
                m = fmaxf(m, lv[d]);
            }
            float s = 0.f;
#pragma unroll
            for (int d = 0; d < K2; d++) { lv[d] = __expf(lv[d] - m); s += lv[d]; }
            const float inv = 1.f / s;
#pragma unroll
            for (int d = 0; d < K2; d++) *(short*)&Pd[d] = f2bs(lv[d] * inv);
        }
    }
    __syncthreads();

    // ---- stage B: effective 5x5 weights
    for (int e = t; e < 2400; e += 384) {
        const int px = e / 300, rem = e % 300;
        const int off = rem / 12, n = rem % 12;
        const int dy = off / 5 - 2, dx = off % 5 - 2;
        const int ir_lo = max(0, -dy), ir_hi = min(2, 2 - dy);
        const int ic_lo = max(0, -dx), ic_hi = min(2, 2 - dx);
        float wsum = 0.f;
        for (int ir = ir_lo; ir <= ir_hi; ir++)
            for (int ic = ic_lo; ic <= ic_hi; ic++) {
                const int i = ir * 3 + ic;
                const int d = (dy + ir) * 3 + (dx + ic);
                wsum += b2f(P[((px * 9 + i) * 12 + n) * 9 + d]);
            }
        Wf[e] = wsum;  // e == (px*25 + off)*12 + n
    }
    __syncthreads();

    // ---- stage C: apply 5x5 gather
    const int px = t / 48, cg = t % 48;
    const int X = X0 + px;
    const int n = cg >> 2;
    const float* Wp = &Wf[px * 300];
    const bf16* vb = vT + (size_t)b * PP * DIM;
    float acc[8] = {};
#pragma unroll
    for (int dy = -2; dy <= 2; dy++) {
        const int ny = Y + dy;              // block-uniform branch
        if (ny < 0 || ny >= HH) continue;
#pragma unroll
        for (int dx = -2; dx <= 2; dx++) {
            const int nx = X + dx;
            const bool ok = (nx >= 0 && nx < WW);
            const int nxc = min(max(nx, 0), WW - 1);
            const float w = ok ? Wp[((dy + 2) * 5 + dx + 2) * 12 + n] : 0.f;
            bf16x8 vv = *(const bf16x8*)(vb + (size_t)(ny * WW + nxc) * DIM + cg * 8);
#pragma unroll
            for (int j = 0; j < 8; j++) acc[j] += w * bs2f(vv[j]);
        }
    }
    bf16x8 po;
#pragma unroll
    for (int j = 0; j < 8; j++) po[j] = f2bs(acc[j]);
    *(bf16x8*)(cT + ((size_t)b * PP + pix0 + px) * DIM + cg * 8) = po;
}

// ---------------------------------------------------------------------------
extern "C" void kernel_launch(void* const* d_in, const int* in_sizes, int n_in,
                              void* d_out, int out_size, void* d_ws, size_t ws_size,
                              hipStream_t stream) {
    const float* x      = (const float*)d_in[0];
    const float* v_w    = (const float*)d_in[1];
    const float* v_b    = (const float*)d_in[2];
    const float* attn_w = (const float*)d_in[3];
    const float* proj_w = (const float*)d_in[4];
    float* out = (float*)d_out;

    bf16* xT    = (bf16*)d_ws;                        // [8][3200][384]
    bf16* vT    = xT + (size_t)BB * PP * DIM;         // [8][3200][384]
    bf16* lT    = vT + (size_t)BB * PP * DIM;         // [8][3200][1024]
    bf16* wcat  = lT + (size_t)BB * PP * AOP;         // [1408][384]
    bf16* wp    = wcat + (size_t)MCAT * DIM;          // [384][384]
    bf16* cT    = xT;   // canvasT aliases xT (xT dead after gemm12)

    const int NW = MCAT * DIM + 384 * DIM;
    wconv_all_kernel<<<(NW + 255) / 256, 256, 0, stream>>>(v_w, attn_w, proj_w, wcat, wp);
    xpose_kernel<<<dim3(PP / 64, BB), 256, 0, stream>>>(x, xT);

    // 1+2) value projection + attention logits (merged)
    gemm12_kernel<<<dim3(PP / 128, MCAT / 128, BB), 256, 0, stream>>>(wcat, xT, v_b, vT, lT);
    // 3) fused softmax + weight-reduce + 5x5 gather -> cT
    attn_fold_kernel<<<dim3(HWP / 8, BB), 384, 0, stream>>>(lT, vT, cT);
    // 4) output projection -> out (planar fp32)
    gemm_planar_kernel<<<dim3(PP / 128, 3, BB), 256, 0, stream>>>(wp, cT, out);
}

// Round 10
// 224.184 us; speedup vs baseline: 1.1531x; 1.1531x over previous
//
#include <hip/hip_runtime.h>
#include <hip/hip_bf16.h>

#define DIM   384
#define HEADS 12
#define K2    9
#define HH    56
#define WW    56
#define HWP   3136
#define BB    8
#define AO    972      // attn-logit channels
#define AOP   1024     // padded (lT row stride)
#define MCAT  1408     // 384 (v) + 1024 (attn) concatenated GEMM rows
#define PP    3200     // pixels padded to 25*128

typedef __hip_bfloat16 bf16;
typedef short bf16x8 __attribute__((ext_vector_type(8)));
typedef short bf16x4v __attribute__((ext_vector_type(4)));
typedef float f32x4 __attribute__((ext_vector_type(4)));

static __device__ __forceinline__ float b2f(bf16 v) { return __bfloat162float(v); }
static __device__ __forceinline__ float bs2f(short s) {
    return __uint_as_float(((unsigned int)(unsigned short)s) << 16);
}
static __device__ __forceinline__ short f2bs(float f) {
    __hip_bfloat16 h = __float2bfloat16(f);
    return *(short*)&h;
}

// async global->LDS, 16B per lane. LDS dest must be wave-uniform base + lane*16.
static __device__ __forceinline__ void gl_lds16(const bf16* g, bf16* l) {
    __builtin_amdgcn_global_load_lds(
        (const __attribute__((address_space(1))) unsigned int*)g,
        (__attribute__((address_space(3))) unsigned int*)l, 16, 0, 0);
}

// ---------------------------------------------------------------------------
// x [b][384][3136] fp32  ->  xT [b][3200][384] bf16 (zero pad rows)
// ---------------------------------------------------------------------------
__global__ __launch_bounds__(256) void xpose_kernel(
        const float* __restrict__ x, bf16* __restrict__ xT) {
    const int lane = threadIdx.x & 63, w = threadIdx.x >> 6;
    const int p = blockIdx.x * 64 + lane;
    const int b = blockIdx.y;
    bf16* dst = xT + ((size_t)b * PP + p) * DIM;
    if (p >= HWP) {
        bf16x8 z = {};
        for (int cg = w; cg < 48; cg += 4) *(bf16x8*)(dst + cg * 8) = z;
        return;
    }
    const float* src = x + (size_t)b * DIM * HWP + p;
    for (int cg = w; cg < 48; cg += 4) {
        bf16x8 v;
#pragma unroll
        for (int j = 0; j < 8; j++) v[j] = f2bs(src[(size_t)(cg * 8 + j) * HWP]);
        *(bf16x8*)(dst + cg * 8) = v;
    }
}

// all three weight tensors -> bf16 in one launch
// wcat = [v_w(384) ; attn_w(972) ; zeros(52)], wp = proj_w
__global__ __launch_bounds__(256) void wconv_all_kernel(
        const float* __restrict__ v_w, const float* __restrict__ attn_w,
        const float* __restrict__ proj_w, bf16* __restrict__ wcat,
        bf16* __restrict__ wp) {
    const int idx = blockIdx.x * 256 + threadIdx.x;
    const int NCAT = MCAT * DIM;
    if (idx < NCAT) {
        const int row = idx / DIM, col = idx % DIM;
        float v;
        if (row < 384) v = v_w[row * DIM + col];
        else { const int r2 = row - 384; v = (r2 < AO) ? attn_w[r2 * DIM + col] : 0.f; }
        *(short*)&wcat[idx] = f2bs(v);
    } else {
        const int j = idx - NCAT;
        if (j < 384 * DIM) *(short*)&wp[j] = f2bs(proj_w[j]);
    }
}

// ---------------------------------------------------------------------------
// GEMM main loop v3: 128x128 tile, BK=32, 4 waves x (4x4) 16x16x32 MFMA.
// Both tiles staged via global_load_lds (VGPR stays ~64) with XOR swizzle:
// k-octet q of row m stored at LDS position (q+(m>>1))&3 (achieved by
// swizzling the GLOBAL source address; LDS dest stays lane-linear as the
// hardware requires). Readers add swz -> 16 reader lanes span all 8 LDS
// 16B-granule groups (2 lanes/granule = conflict-free; was 8-way).
// ---------------------------------------------------------------------------
#define GEMM_MAIN_LOOP_V3(Ab, Bb, lA, lB, acc)                                 \
    {                                                                          \
    const int swz = ((quad + (l16 >> 1)) & 3) * 8;                             \
    for (int k0 = 0; k0 < DIM; k0 += 32) {                                     \
        _Pragma("unroll")                                                      \
        for (int r = 0; r < 2; r++) {                                          \
            int idx = r * 256 + t;                                             \
            int row = idx >> 2;                                                \
            int kq = ((idx & 3) - (row >> 1)) & 3;                             \
            gl_lds16(Ab + (size_t)row * DIM + k0 + kq * 8, lA + idx * 8);      \
        }                                                                      \
        _Pragma("unroll")                                                      \
        for (int r = 0; r < 2; r++) {                                          \
            int idx = r * 256 + t;                                             \
            int row = idx >> 2;                                                \
            int kq = ((idx & 3) - (row >> 1)) & 3;                             \
            gl_lds16(Bb + (size_t)row * DIM + k0 + kq * 8, lB + idx * 8);      \
        }                                                                      \
        __syncthreads();                                                       \
        bf16x8 af[4], bfr[4];                                                  \
        _Pragma("unroll")                                                      \
        for (int mt = 0; mt < 4; mt++)                                         \
            af[mt] = *(const bf16x8*)(lA + (wm * 64 + mt * 16 + l16) * 32 + swz); \
        _Pragma("unroll")                                                      \
        for (int nt = 0; nt < 4; nt++)                                         \
            bfr[nt] = *(const bf16x8*)(lB + (wn * 64 + nt * 16 + l16) * 32 + swz); \
        _Pragma("unroll")                                                      \
        for (int mt = 0; mt < 4; mt++)                                         \
            _Pragma("unroll")                                                  \
            for (int nt = 0; nt < 4; nt++)                                     \
                acc[mt][nt] = __builtin_amdgcn_mfma_f32_16x16x32_bf16(         \
                    af[mt], bfr[nt], acc[mt][nt], 0, 0, 0);                    \
        __syncthreads();                                                       \
    }                                                                          \
    }

// ---------------------------------------------------------------------------
// Merged GEMM1+2: A = [wv(384) ; wa(1024)] -> vT (stride 384, +bias) and
// lT (stride 1024). Transposed bf16 outputs via per-wave LDS repack
// (no barriers: wbuf regions are wave-private; DS ops are wave-ordered;
// lA/lB are dead after the final main-loop barrier).
// ---------------------------------------------------------------------------
__global__ __launch_bounds__(256) void gemm12_kernel(
        const bf16* __restrict__ A, const bf16* __restrict__ Bt,
        const float* __restrict__ bias, bf16* __restrict__ vT,
        bf16* __restrict__ lT) {
    __shared__ bf16 lds[8192];          // lA 4096 | lB 4096 (reused as wbuf)
    bf16* lA = lds;
    bf16* lB = lds + 4096;
    const int t = threadIdx.x;
    const int lane = t & 63, w = t >> 6;
    const int wm = w & 1, wn = w >> 1;
    const int quad = lane >> 4, l16 = lane & 15;
    const int n0 = blockIdx.x * 128;
    const int m0 = blockIdx.y * 128;
    const int b = blockIdx.z;

    const bf16* Ab = A + (size_t)m0 * DIM;
    const bf16* Bb = Bt + ((size_t)b * PP + n0) * DIM;

    f32x4 acc[4][4] = {};
    GEMM_MAIN_LOOP_V3(Ab, Bb, lA, lB, acc)

    const bool isv = (m0 < 384);
    bf16* outp = isv ? vT : lT;
    const int ostr = isv ? DIM : AOP;
    const int ch0 = isv ? m0 : m0 - 384;

    bf16* wbuf = lds + w * 1152;   // wave-private, row stride 72 bf16
    const int nr = lane >> 2;
    const int mc = (lane & 3) * 16;
#pragma unroll
    for (int nt = 0; nt < 4; nt++) {
#pragma unroll
        for (int mt = 0; mt < 4; mt++) {
            float4 bi = make_float4(0.f, 0.f, 0.f, 0.f);
            if (isv) bi = *(const float4*)(bias + ch0 + wm * 64 + mt * 16 + quad * 4);
            bf16x4v pk;
            pk[0] = f2bs(acc[mt][nt][0] + bi.x);
            pk[1] = f2bs(acc[mt][nt][1] + bi.y);
            pk[2] = f2bs(acc[mt][nt][2] + bi.z);
            pk[3] = f2bs(acc[mt][nt][3] + bi.w);
            *(bf16x4v*)(wbuf + l16 * 72 + mt * 16 + quad * 4) = pk;
        }
        bf16x8 v0 = *(const bf16x8*)(wbuf + nr * 72 + mc);
        bf16x8 v1 = *(const bf16x8*)(wbuf + nr * 72 + mc + 8);
        const int p = n0 + wn * 64 + nt * 16 + nr;
        if (p < HWP) {
            bf16* dp = outp + ((size_t)b * PP + p) * ostr + ch0 + wm * 64 + mc;
            *(bf16x8*)dp = v0;
            *(bf16x8*)(dp + 8) = v1;
        }
    }
}

// ---------------------------------------------------------------------------
// GEMM4: planar fp32 out [b][384][3136]
// ---------------------------------------------------------------------------
__global__ __launch_bounds__(256) void gemm_planar_kernel(
        const bf16* __restrict__ A, const bf16* __restrict__ Bt,
        float* __restrict__ out) {
    __shared__ bf16 lds[8192];
    bf16* lA = lds;
    bf16* lB = lds + 4096;
    const int t = threadIdx.x;
    const int lane = t & 63, w = t >> 6;
    const int wm = w & 1, wn = w >> 1;
    const int quad = lane >> 4, l16 = lane & 15;
    const int n0 = blockIdx.x * 128;
    const int m0 = blockIdx.y * 128;
    const int b = blockIdx.z;

    const bf16* Ab = A + (size_t)m0 * DIM;
    const bf16* Bb = Bt + ((size_t)b * PP + n0) * DIM;

    f32x4 acc[4][4] = {};
    GEMM_MAIN_LOOP_V3(Ab, Bb, lA, lB, acc)

#pragma unroll
    for (int mt = 0; mt < 4; mt++) {
#pragma unroll
        for (int nt = 0; nt < 4; nt++) {
            int p = n0 + wn * 64 + nt * 16 + l16;
            if (p >= HWP) continue;
#pragma unroll
            for (int reg = 0; reg < 4; reg++) {
                int o = m0 + wm * 64 + mt * 16 + quad * 4 + reg;
                out[((size_t)b * DIM + o) * HWP + p] = acc[mt][nt][reg];
            }
        }
    }
}

// ---------------------------------------------------------------------------
// attn+fold (unchanged from round 8): 8 pixels per block, 384 threads.
// P stored bf16: LDS 29 KB -> high occupancy; stage-A direct global reads.
// ---------------------------------------------------------------------------
__global__ __launch_bounds__(384) void attn_fold_kernel(
        const bf16* __restrict__ lT, const bf16* __restrict__ vT,
        bf16* __restrict__ cT) {
    __shared__ bf16 P[8 * 9 * 12 * 9];     // [px][i][n][d]  19440 B
    __shared__ float Wf[8 * 25 * 12];      // [px][off][n]    9600 B
    const int t = threadIdx.x;
    const int b = blockIdx.y;
    const int pix0 = blockIdx.x * 8;
    const int Y = pix0 / WW, X0 = pix0 % WW;

    // ---- stage A: softmaxes at window centers (direct global reads)
    for (int r = t; r < 864; r += 384) {
        const int px = r / 108, rem = r % 108;
        const int i = rem / 12, n = rem % 12;
        const int ir = i / 3, ic = i % 3;
        const int yi = Y + 1 - ir, xi = X0 + px + 1 - ic;
        bf16* Pd = &P[r * 9];   // r*9 == ((px*9+i)*12+n)*9
        if (yi < 0 || yi >= HH || xi < 0 || xi >= WW) {
#pragma unroll
            for (int d = 0; d < K2; d++) *(short*)&Pd[d] = 0;
        } else {
            const bf16* base = lT + ((size_t)b * PP + yi * WW + xi) * AOP + i * 108 + n;
            float lv[K2];
            float m = -1e30f;
#pragma unroll
            for (int d = 0; d < K2; d++) {
                lv[d] = b2f(base[d * 12]);
                m = fmaxf(m, lv[d]);
            }
            float s = 0.f;
#pragma unroll
            for (int d = 0; d < K2; d++) { lv[d] = __expf(lv[d] - m); s += lv[d]; }
            const float inv = 1.f / s;
#pragma unroll
            for (int d = 0; d < K2; d++) *(short*)&Pd[d] = f2bs(lv[d] * inv);
        }
    }
    __syncthreads();

    // ---- stage B: effective 5x5 weights
    for (int e = t; e < 2400; e += 384) {
        const int px = e / 300, rem = e % 300;
        const int off = rem / 12, n = rem % 12;
        const int dy = off / 5 - 2, dx = off % 5 - 2;
        const int ir_lo = max(0, -dy), ir_hi = min(2, 2 - dy);
        const int ic_lo = max(0, -dx), ic_hi = min(2, 2 - dx);
        float wsum = 0.f;
        for (int ir = ir_lo; ir <= ir_hi; ir++)
            for (int ic = ic_lo; ic <= ic_hi; ic++) {
                const int i = ir * 3 + ic;
                const int d = (dy + ir) * 3 + (dx + ic);
                wsum += b2f(P[((px * 9 + i) * 12 + n) * 9 + d]);
            }
        Wf[e] = wsum;  // e == (px*25 + off)*12 + n
    }
    __syncthreads();

    // ---- stage C: apply 5x5 gather
    const int px = t / 48, cg = t % 48;
    const int X = X0 + px;
    const int n = cg >> 2;
    const float* Wp = &Wf[px * 300];
    const bf16* vb = vT + (size_t)b * PP * DIM;
    float acc[8] = {};
#pragma unroll
    for (int dy = -2; dy <= 2; dy++) {
        const int ny = Y + dy;              // block-uniform branch
        if (ny < 0 || ny >= HH) continue;
#pragma unroll
        for (int dx = -2; dx <= 2; dx++) {
            const int nx = X + dx;
            const bool ok = (nx >= 0 && nx < WW);
            const int nxc = min(max(nx, 0), WW - 1);
            const float w = ok ? Wp[((dy + 2) * 5 + dx + 2) * 12 + n] : 0.f;
            bf16x8 vv = *(const bf16x8*)(vb + (size_t)(ny * WW + nxc) * DIM + cg * 8);
#pragma unroll
            for (int j = 0; j < 8; j++) acc[j] += w * bs2f(vv[j]);
        }
    }
    bf16x8 po;
#pragma unroll
    for (int j = 0; j < 8; j++) po[j] = f2bs(acc[j]);
    *(bf16x8*)(cT + ((size_t)b * PP + pix0 + px) * DIM + cg * 8) = po;
}

// ---------------------------------------------------------------------------
extern "C" void kernel_launch(void* const* d_in, const int* in_sizes, int n_in,
                              void* d_out, int out_size, void* d_ws, size_t ws_size,
                              hipStream_t stream) {
    const float* x      = (const float*)d_in[0];
    const float* v_w    = (const float*)d_in[1];
    const float* v_b    = (const float*)d_in[2];
    const float* attn_w = (const float*)d_in[3];
    const float* proj_w = (const float*)d_in[4];
    float* out = (float*)d_out;

    bf16* xT    = (bf16*)d_ws;                        // [8][3200][384]
    bf16* vT    = xT + (size_t)BB * PP * DIM;         // [8][3200][384]
    bf16* lT    = vT + (size_t)BB * PP * DIM;         // [8][3200][1024]
    bf16* wcat  = lT + (size_t)BB * PP * AOP;         // [1408][384]
    bf16* wp    = wcat + (size_t)MCAT * DIM;          // [384][384]
    bf16* cT    = xT;   // canvasT aliases xT (xT dead after gemm12)

    const int NW = MCAT * DIM + 384 * DIM;
    wconv_all_kernel<<<(NW + 255) / 256, 256, 0, stream>>>(v_w, attn_w, proj_w, wcat, wp);
    xpose_kernel<<<dim3(PP / 64, BB), 256, 0, stream>>>(x, xT);

    // 1+2) value projection + attention logits (merged)
    gemm12_kernel<<<dim3(PP / 128, MCAT / 128, BB), 256, 0, stream>>>(wcat, xT, v_b, vT, lT);
    // 3) fused softmax + weight-reduce + 5x5 gather -> cT
    attn_fold_kernel<<<dim3(HWP / 8, BB), 384, 0, stream>>>(lT, vT, cT);
    // 4) output projection -> out (planar fp32)
    gemm_planar_kernel<<<dim3(PP / 128, 3, BB), 256, 0, stream>>>(wp, cT, out);
}

// Round 11
// 219.992 us; speedup vs baseline: 1.1751x; 1.0191x over previous
//
#include <hip/hip_runtime.h>
#include <hip/hip_bf16.h>

#define DIM   384
#define HEADS 12
#define K2    9
#define HH    56
#define WW    56
#define HWP   3136
#define BB    8
#define AO    972      // attn-logit channels
#define AOP   1024     // padded (lT row stride)
#define MCAT  1408     // 384 (v) + 1024 (attn) concatenated GEMM rows
#define PP    3200     // pixels padded to 25*128

typedef __hip_bfloat16 bf16;
typedef short bf16x8 __attribute__((ext_vector_type(8)));
typedef short bf16x4v __attribute__((ext_vector_type(4)));
typedef float f32x4 __attribute__((ext_vector_type(4)));

static __device__ __forceinline__ float b2f(bf16 v) { return __bfloat162float(v); }
static __device__ __forceinline__ float bs2f(short s) {
    return __uint_as_float(((unsigned int)(unsigned short)s) << 16);
}
static __device__ __forceinline__ short f2bs(float f) {
    __hip_bfloat16 h = __float2bfloat16(f);
    return *(short*)&h;
}

// async global->LDS, 16B per lane. LDS dest must be wave-uniform base + lane*16.
static __device__ __forceinline__ void gl_lds16(const bf16* g, bf16* l) {
    __builtin_amdgcn_global_load_lds(
        (const __attribute__((address_space(1))) unsigned int*)g,
        (__attribute__((address_space(3))) unsigned int*)l, 16, 0, 0);
}

// ---------------------------------------------------------------------------
// Fused prep: weights->bf16 (wcat, wp) AND x -> xT transpose, one launch.
// blocks [0, 400):   xpose: x [b][384][3136] fp32 -> xT [b][3200][384] bf16
// blocks [400, ...): wconv: wcat = [v_w ; attn_w ; 0pad], wp = proj_w
// ---------------------------------------------------------------------------
__global__ __launch_bounds__(256) void prep_kernel(
        const float* __restrict__ x, const float* __restrict__ v_w,
        const float* __restrict__ attn_w, const float* __restrict__ proj_w,
        bf16* __restrict__ xT, bf16* __restrict__ wcat, bf16* __restrict__ wp) {
    const int bid = blockIdx.x;
    if (bid < 400) {
        const int lane = threadIdx.x & 63, w = threadIdx.x >> 6;
        const int p = (bid % 50) * 64 + lane;
        const int b = bid / 50;
        bf16* dst = xT + ((size_t)b * PP + p) * DIM;
        if (p >= HWP) {
            bf16x8 z = {};
            for (int cg = w; cg < 48; cg += 4) *(bf16x8*)(dst + cg * 8) = z;
            return;
        }
        const float* src = x + (size_t)b * DIM * HWP + p;
        for (int cg = w; cg < 48; cg += 4) {
            bf16x8 v;
#pragma unroll
            for (int j = 0; j < 8; j++) v[j] = f2bs(src[(size_t)(cg * 8 + j) * HWP]);
            *(bf16x8*)(dst + cg * 8) = v;
        }
    } else {
        const int idx = (bid - 400) * 256 + threadIdx.x;
        const int NCAT = MCAT * DIM;
        if (idx < NCAT) {
            const int row = idx / DIM, col = idx % DIM;
            float v;
            if (row < 384) v = v_w[row * DIM + col];
            else { const int r2 = row - 384; v = (r2 < AO) ? attn_w[r2 * DIM + col] : 0.f; }
            *(short*)&wcat[idx] = f2bs(v);
        } else {
            const int j = idx - NCAT;
            if (j < 384 * DIM) *(short*)&wp[j] = f2bs(proj_w[j]);
        }
    }
}

// ---------------------------------------------------------------------------
// GEMM main loop v4: 128x128 tile, BK=64 (6 k-iters: half the barrier drains
// of BK=32), 4 waves x (4x4) 16x16x32 MFMA, 2 k-half-steps per iter.
// Both tiles staged via global_load_lds with 8-position XOR swizzle:
// k-octet kq of row m stored at LDS octet (kq + (m>>1)) & 7 (swizzle applied
// on the GLOBAL source address; LDS dest stays lane-linear). Readers add
// ((h*4+quad + (l16>>1)) & 7)*8 -> 2 lanes/granule, conflict-free.
// LDS row stride = 64 ch (128 B).
// ---------------------------------------------------------------------------
#define GEMM_MAIN_LOOP_V4(Ab, Bb, lA, lB, acc)                                 \
    for (int k0 = 0; k0 < DIM; k0 += 64) {                                     \
        _Pragma("unroll")                                                      \
        for (int r = 0; r < 4; r++) {                                          \
            int idx = r * 256 + t;                                             \
            int row = idx >> 3;                                                \
            int kq = ((idx & 7) - (row >> 1)) & 7;                             \
            gl_lds16(Ab + (size_t)row * DIM + k0 + kq * 8, lA + idx * 8);      \
        }                                                                      \
        _Pragma("unroll")                                                      \
        for (int r = 0; r < 4; r++) {                                          \
            int idx = r * 256 + t;                                             \
            int row = idx >> 3;                                                \
            int kq = ((idx & 7) - (row >> 1)) & 7;                             \
            gl_lds16(Bb + (size_t)row * DIM + k0 + kq * 8, lB + idx * 8);      \
        }                                                                      \
        __syncthreads();                                                       \
        _Pragma("unroll")                                                      \
        for (int h = 0; h < 2; h++) {                                          \
            const int swzh = (((h << 2) + quad + (l16 >> 1)) & 7) * 8;         \
            bf16x8 af[4], bfr[4];                                              \
            _Pragma("unroll")                                                  \
            for (int mt = 0; mt < 4; mt++)                                     \
                af[mt] = *(const bf16x8*)(lA + (wm * 64 + mt * 16 + l16) * 64 + swzh); \
            _Pragma("unroll")                                                  \
            for (int nt = 0; nt < 4; nt++)                                     \
                bfr[nt] = *(const bf16x8*)(lB + (wn * 64 + nt * 16 + l16) * 64 + swzh); \
            _Pragma("unroll")                                                  \
            for (int mt = 0; mt < 4; mt++)                                     \
                _Pragma("unroll")                                              \
                for (int nt = 0; nt < 4; nt++)                                 \
                    acc[mt][nt] = __builtin_amdgcn_mfma_f32_16x16x32_bf16(     \
                        af[mt], bfr[nt], acc[mt][nt], 0, 0, 0);                \
        }                                                                      \
        __syncthreads();                                                       \
    }

// ---------------------------------------------------------------------------
// Merged GEMM1+2: A = [wv(384) ; wa(1024)] -> vT (stride 384, +bias) and
// lT (stride 1024). Transposed bf16 outputs via per-wave LDS repack
// (no barriers: wbuf regions are wave-private; DS ops are wave-ordered;
// lA/lB dead after final main-loop barrier).
// ---------------------------------------------------------------------------
__global__ __launch_bounds__(256) void gemm12_kernel(
        const bf16* __restrict__ A, const bf16* __restrict__ Bt,
        const float* __restrict__ bias, bf16* __restrict__ vT,
        bf16* __restrict__ lT) {
    __shared__ bf16 lds[16384];         // lA 8192 ch | lB 8192 ch (32 KB)
    bf16* lA = lds;
    bf16* lB = lds + 8192;
    const int t = threadIdx.x;
    const int lane = t & 63, w = t >> 6;
    const int wm = w & 1, wn = w >> 1;
    const int quad = lane >> 4, l16 = lane & 15;
    const int n0 = blockIdx.x * 128;
    const int m0 = blockIdx.y * 128;
    const int b = blockIdx.z;

    const bf16* Ab = A + (size_t)m0 * DIM;
    const bf16* Bb = Bt + ((size_t)b * PP + n0) * DIM;

    f32x4 acc[4][4] = {};
    GEMM_MAIN_LOOP_V4(Ab, Bb, lA, lB, acc)

    const bool isv = (m0 < 384);
    bf16* outp = isv ? vT : lT;
    const int ostr = isv ? DIM : AOP;
    const int ch0 = isv ? m0 : m0 - 384;

    bf16* wbuf = lds + w * 1152;   // wave-private, row stride 72 bf16
    const int nr = lane >> 2;
    const int mc = (lane & 3) * 16;
#pragma unroll
    for (int nt = 0; nt < 4; nt++) {
#pragma unroll
        for (int mt = 0; mt < 4; mt++) {
            float4 bi = make_float4(0.f, 0.f, 0.f, 0.f);
            if (isv) bi = *(const float4*)(bias + ch0 + wm * 64 + mt * 16 + quad * 4);
            bf16x4v pk;
            pk[0] = f2bs(acc[mt][nt][0] + bi.x);
            pk[1] = f2bs(acc[mt][nt][1] + bi.y);
            pk[2] = f2bs(acc[mt][nt][2] + bi.z);
            pk[3] = f2bs(acc[mt][nt][3] + bi.w);
            *(bf16x4v*)(wbuf + l16 * 72 + mt * 16 + quad * 4) = pk;
        }
        bf16x8 v0 = *(const bf16x8*)(wbuf + nr * 72 + mc);
        bf16x8 v1 = *(const bf16x8*)(wbuf + nr * 72 + mc + 8);
        const int p = n0 + wn * 64 + nt * 16 + nr;
        if (p < HWP) {
            bf16* dp = outp + ((size_t)b * PP + p) * ostr + ch0 + wm * 64 + mc;
            *(bf16x8*)dp = v0;
            *(bf16x8*)(dp + 8) = v1;
        }
    }
}

// ---------------------------------------------------------------------------
// GEMM4: planar fp32 out [b][384][3136]
// ---------------------------------------------------------------------------
__global__ __launch_bounds__(256) void gemm_planar_kernel(
        const bf16* __restrict__ A, const bf16* __restrict__ Bt,
        float* __restrict__ out) {
    __shared__ bf16 lds[16384];
    bf16* lA = lds;
    bf16* lB = lds + 8192;
    const int t = threadIdx.x;
    const int lane = t & 63, w = t >> 6;
    const int wm = w & 1, wn = w >> 1;
    const int quad = lane >> 4, l16 = lane & 15;
    const int n0 = blockIdx.x * 128;
    const int m0 = blockIdx.y * 128;
    const int b = blockIdx.z;

    const bf16* Ab = A + (size_t)m0 * DIM;
    const bf16* Bb = Bt + ((size_t)b * PP + n0) * DIM;

    f32x4 acc[4][4] = {};
    GEMM_MAIN_LOOP_V4(Ab, Bb, lA, lB, acc)

#pragma unroll
    for (int mt = 0; mt < 4; mt++) {
#pragma unroll
        for (int nt = 0; nt < 4; nt++) {
            int p = n0 + wn * 64 + nt * 16 + l16;
            if (p >= HWP) continue;
#pragma unroll
            for (int reg = 0; reg < 4; reg++) {
                int o = m0 + wm * 64 + mt * 16 + quad * 4 + reg;
                out[((size_t)b * DIM + o) * HWP + p] = acc[mt][nt][reg];
            }
        }
    }
}

// ---------------------------------------------------------------------------
// attn+fold (unchanged from round 8): 8 pixels per block, 384 threads.
// P stored bf16: LDS 29 KB -> high occupancy; stage-A direct global reads.
// ---------------------------------------------------------------------------
__global__ __launch_bounds__(384) void attn_fold_kernel(
        const bf16* __restrict__ lT, const bf16* __restrict__ vT,
        bf16* __restrict__ cT) {
    __shared__ bf16 P[8 * 9 * 12 * 9];     // [px][i][n][d]  19440 B
    __shared__ float Wf[8 * 25 * 12];      // [px][off][n]    9600 B
    const int t = threadIdx.x;
    const int b = blockIdx.y;
    const int pix0 = blockIdx.x * 8;
    const int Y = pix0 / WW, X0 = pix0 % WW;

    // ---- stage A: softmaxes at window centers (direct global reads)
    for (int r = t; r < 864; r += 384) {
        const int px = r / 108, rem = r % 108;
        const int i = rem / 12, n = rem % 12;
        const int ir = i / 3, ic = i % 3;
        const int yi = Y + 1 - ir, xi = X0 + px + 1 - ic;
        bf16* Pd = &P[r * 9];   // r*9 == ((px*9+i)*12+n)*9
        if (yi < 0 || yi >= HH || xi < 0 || xi >= WW) {
#pragma unroll
            for (int d = 0; d < K2; d++) *(short*)&Pd[d] = 0;
        } else {
            const bf16* base = lT + ((size_t)b * PP + yi * WW + xi) * AOP + i * 108 + n;
            float lv[K2];
            float m = -1e30f;
#pragma unroll
            for (int d = 0; d < K2; d++) {
                lv[d] = b2f(base[d * 12]);
                m = fmaxf(m, lv[d]);
            }
            float s = 0.f;
#pragma unroll
            for (int d = 0; d < K2; d++) { lv[d] = __expf(lv[d] - m); s += lv[d]; }
            const float inv = 1.f / s;
#pragma unroll
            for (int d = 0; d < K2; d++) *(short*)&Pd[d] = f2bs(lv[d] * inv);
        }
    }
    __syncthreads();

    // ---- stage B: effective 5x5 weights
    for (int e = t; e < 2400; e += 384) {
        const int px = e / 300, rem = e % 300;
        const int off = rem / 12, n = rem % 12;
        const int dy = off / 5 - 2, dx = off % 5 - 2;
        const int ir_lo = max(0, -dy), ir_hi = min(2, 2 - dy);
        const int ic_lo = max(0, -dx), ic_hi = min(2, 2 - dx);
        float wsum = 0.f;
        for (int ir = ir_lo; ir <= ir_hi; ir++)
            for (int ic = ic_lo; ic <= ic_hi; ic++) {
                const int i = ir * 3 + ic;
                const int d = (dy + ir) * 3 + (dx + ic);
                wsum += b2f(P[((px * 9 + i) * 12 + n) * 9 + d]);
            }
        Wf[e] = wsum;  // e == (px*25 + off)*12 + n
    }
    __syncthreads();

    // ---- stage C: apply 5x5 gather
    const int px = t / 48, cg = t % 48;
    const int X = X0 + px;
    const int n = cg >> 2;
    const float* Wp = &Wf[px * 300];
    const bf16* vb = vT + (size_t)b * PP * DIM;
    float acc[8] = {};
#pragma unroll
    for (int dy = -2; dy <= 2; dy++) {
        const int ny = Y + dy;              // block-uniform branch
        if (ny < 0 || ny >= HH) continue;
#pragma unroll
        for (int dx = -2; dx <= 2; dx++) {
            const int nx = X + dx;
            const bool ok = (nx >= 0 && nx < WW);
            const int nxc = min(max(nx, 0), WW - 1);
            const float w = ok ? Wp[((dy + 2) * 5 + dx + 2) * 12 + n] : 0.f;
            bf16x8 vv = *(const bf16x8*)(vb + (size_t)(ny * WW + nxc) * DIM + cg * 8);
#pragma unroll
            for (int j = 0; j < 8; j++) acc[j] += w * bs2f(vv[j]);
        }
    }
    bf16x8 po;
#pragma unroll
    for (int j = 0; j < 8; j++) po[j] = f2bs(acc[j]);
    *(bf16x8*)(cT + ((size_t)b * PP + pix0 + px) * DIM + cg * 8) = po;
}

// ---------------------------------------------------------------------------
extern "C" void kernel_launch(void* const* d_in, const int* in_sizes, int n_in,
                              void* d_out, int out_size, void* d_ws, size_t ws_size,
                              hipStream_t stream) {
    const float* x      = (const float*)d_in[0];
    const float* v_w    = (const float*)d_in[1];
    const float* v_b    = (const float*)d_in[2];
    const float* attn_w = (const float*)d_in[3];
    const float* proj_w = (const float*)d_in[4];
    float* out = (float*)d_out;

    bf16* xT    = (bf16*)d_ws;                        // [8][3200][384]
    bf16* vT    = xT + (size_t)BB * PP * DIM;         // [8][3200][384]
    bf16* lT    = vT + (size_t)BB * PP * DIM;         // [8][3200][1024]
    bf16* wcat  = lT + (size_t)BB * PP * AOP;         // [1408][384]
    bf16* wp    = wcat + (size_t)MCAT * DIM;          // [384][384]
    bf16* cT    = xT;   // canvasT aliases xT (xT dead after gemm12)

    const int NW = MCAT * DIM + 384 * DIM;
    const int nprep = 400 + (NW + 255) / 256;
    prep_kernel<<<nprep, 256, 0, stream>>>(x, v_w, attn_w, proj_w, xT, wcat, wp);

    // 1+2) value projection + attention logits (merged)
    gemm12_kernel<<<dim3(PP / 128, MCAT / 128, BB), 256, 0, stream>>>(wcat, xT, v_b, vT, lT);
    // 3) fused softmax + weight-reduce + 5x5 gather -> cT
    attn_fold_kernel<<<dim3(HWP / 8, BB), 384, 0, stream>>>(lT, vT, cT);
    // 4) output projection -> out (planar fp32)
    gemm_planar_kernel<<<dim3(PP / 128, 3, BB), 256, 0, stream>>>(wp, cT, out);
}